// Round 2
// baseline (2617.066 us; speedup 1.0000x reference)
//
#include <hip/hip_runtime.h>
#include <hip/hip_bf16.h>

typedef unsigned short u16;
typedef unsigned int u32;
typedef unsigned long long u64;
typedef __attribute__((ext_vector_type(8))) short bf16x8;   // 8 bf16 (4 VGPRs)
typedef __attribute__((ext_vector_type(4))) float f32x4;

#define MFMA(a,b,c) __builtin_amdgcn_mfma_f32_16x16x32_bf16((a),(b),(c),0,0,0)
#define AGENT __HIP_MEMORY_SCOPE_AGENT
#define WGSC  __HIP_MEMORY_SCOPE_WORKGROUP

// v3: hybrid L2-local/IC polling, no placement assumption for correctness.
// Producers: AGENT relaxed atomic stores (v1-identical: write-through IC;
// same-XCD L2 copy updated-or-invalidated on hit -> local readers fresh).
// Consumers: fast rounds = buffer_inv sc0 (vector-L1 invalidate, the gfx940+
// acquire-fence instruction) + plain loads served by the XCD L2; every 8th
// round = AGENT load (IC, always fresh) so a wrong wg->XCD mapping degrades
// to v1 speed instead of hanging. rowgroup = wg&7 so under round-robin
// dispatch all 32 communicating wgs share one XCD and fast rounds hit.
// cc5 RMW counter removed (IC-side RMW leaves L2 copies stale -> unpollable
// locally); GRU5's WAR guard instead polls h6 tags: h6 tag t-1 in slot t&1
// proves GRU6 finished iter t-1, hence staged h5[t-2]. Guard runs before the
// pre-MFMA barrier (off the post-MFMA critical region). zin staged to regs.
//
// B=128, T=512, LAT=256, F2=64, H=512, DIN=320, 3H=1536
// 256 wgs: rgp = wg&7 (8 rowgroups of 16 rows), rid = wg>>3 (0..31):
//   rid<16 -> GRU5 slice=rid; rid>=16 -> GRU6 slice=rid-16 (32 h-cols each)
// iter t (514): GRU5 -> h5[t] (t<512); GRU6 -> h6[t-1] (1<=t<=512);
//               dec[t-2] from LDS-staged h6[t-2] (t>=2). Parity s&1 in ws.
// Tags: every h word u32 = (step_tag<<16)|bf16, self-validating per word.

__device__ __forceinline__ u16 f2bf(float f) {
    u32 u = __float_as_uint(f);
    u32 r = (u + 0x7fffu + ((u >> 16) & 1u)) >> 16;
    return (u16)r;
}
__device__ __forceinline__ float bf2f(u16 v) { return __uint_as_float(((u32)v) << 16); }
__device__ __forceinline__ float sat01(float x) { return fminf(1.f, fmaxf(0.f, x)); }
__device__ __forceinline__ float ftanh(float x) {
    x = fminf(10.f, fmaxf(-10.f, x));
    float e = __expf(2.f * x);
    return (e - 1.f) / (e + 1.f);
}

// Invalidate this CU's vector L1 so subsequent plain loads are served by the
// XCD's L2 (the same-XCD coherence point). vmcnt(0) first so no in-flight
// load refills a stale line after the invalidate.
__device__ __forceinline__ void l1_inv() {
    asm volatile("s_waitcnt vmcnt(0)\n\tbuffer_inv sc0" ::: "memory");
}

__device__ __forceinline__ bf16x8 loadB(const float* __restrict__ M, int k0, int colbase,
                                        int l15, int q8) {
    const float* p = M + (size_t)(k0 + q8) * 1536 + colbase + l15;
    bf16x8 r;
#pragma unroll
    for (int j = 0; j < 8; ++j) r[j] = (short)f2bf(p[(size_t)j * 1536]);
    return r;
}

__device__ __forceinline__ bf16x8 ldsA(const u16* s, int stride, int colbase, int l15, int q8) {
    return *(const bf16x8*)(s + l15 * stride + colbase + q8);
}

__global__ void zero_ws_kernel(u32* ws) {
    int i = blockIdx.x * 256 + threadIdx.x;
    if (i < 262144) ws[i] = 0u;  // h5w[2][128][512] + h6w[2][128][512]
}

__global__ void __launch_bounds__(256, 1)
gru_fused(const float* __restrict__ zin, const float* __restrict__ x2,
          const float* __restrict__ msk, const float* __restrict__ dmsk,
          const float* __restrict__ W5, const float* __restrict__ U5,
          const float* __restrict__ bi5, const float* __restrict__ br5,
          const float* __restrict__ W6, const float* __restrict__ U6,
          const float* __restrict__ bi6, const float* __restrict__ br6,
          const float* __restrict__ Wd, const float* __restrict__ bdp,
          float* __restrict__ out, u32* __restrict__ h5w,
          u32* __restrict__ h6w)
{
    const int wg = blockIdx.x;
    const int rgp = wg & 7;          // rowgroup -> XCD under round-robin dispatch
    const int rid = wg >> 3;         // 0..31 role within rowgroup
    const bool is6 = rid >= 16;
    const int slice = is6 ? (rid - 16) : rid;
    const int row0 = rgp << 4;
    const int sb = slice << 5;
    const int tid = threadIdx.x;
    const int wv = tid >> 6, lane = tid & 63;
    const int l15 = lane & 15, q8 = (lane >> 4) << 3;

    __shared__ u16 stg[16 * 1032];
    __shared__ float exch[8 * 16 * 17];

    const int ct = wv & 1;
    const int gMain = (wv < 2) ? 0 : 1;
    const int colMain = gMain * 512 + sb + ct * 16;
    const int colH = 1024 + sb + ct * 16;

    const float* bi = is6 ? bi6 : bi5;
    const float* br = is6 ? br6 : br5;
    const float biasM = bi[colMain + l15] + br[colMain + l15];
    const float biasS = (wv < 2) ? bi[colH + l15] : br[colH + l15];

    bf16x8 Bm[32], Bs[16];
    if (!is6) {
#pragma unroll
        for (int kt = 0; kt < 10; ++kt) Bm[kt] = loadB(W5, kt * 32, colMain, l15, q8);
#pragma unroll
        for (int kt = 0; kt < 16; ++kt) Bm[10 + kt] = loadB(U5, kt * 32, colMain, l15, q8);
        if (wv < 2) {
#pragma unroll
            for (int kt = 0; kt < 10; ++kt) Bs[kt] = loadB(W5, kt * 32, colH, l15, q8);
        } else {
#pragma unroll
            for (int kt = 0; kt < 16; ++kt) Bs[kt] = loadB(U5, kt * 32, colH, l15, q8);
        }
    } else {
#pragma unroll
        for (int kt = 0; kt < 16; ++kt) Bm[kt] = loadB(W6, kt * 32, colMain, l15, q8);
#pragma unroll
        for (int kt = 0; kt < 16; ++kt) Bm[16 + kt] = loadB(U6, kt * 32, colMain, l15, q8);
        if (wv < 2) {
#pragma unroll
            for (int kt = 0; kt < 16; ++kt) Bs[kt] = loadB(W6, kt * 32, colH, l15, q8);
        } else {
#pragma unroll
            for (int kt = 0; kt < 16; ++kt) Bs[kt] = loadB(U6, kt * 32, colH, l15, q8);
        }
    }

    float wdv[8]; float bdv = 0.f;
    if (is6 && wv == 0) {
#pragma unroll
        for (int j = 0; j < 8; ++j) wdv[j] = Wd[lane * 8 + j];
        bdv = bdp[0];
    }

    const int grow = tid >> 4, cp = tid & 15;
    const int c2p = cp >> 3, ccb = (cp & 7) * 2;
    const int r_ = tid >> 4, cth = tid & 15;
    const int b_ = row0 + r_;

    // zin row is t-invariant: stage once to registers (16 f32/thread)
    float zreg[16];
#pragma unroll
    for (int k = 0; k < 16; ++k) zreg[k] = zin[(size_t)b_ * 256 + cth + 16 * k];

    float hold0 = 0.f, hold1 = 0.f;

    for (int t = 0; t < 514; ++t) {
        if (!is6) {
            if (t < 512) {
                // ---- stage masked x (independent of h; issued first) ----
                float mk = msk[b_ * 512 + t];
#pragma unroll
                for (int k = 0; k < 16; ++k)
                    stg[r_ * 840 + cth + 16 * k] = f2bf(zreg[k] * mk);
#pragma unroll
                for (int k = 0; k < 4; ++k) {
                    float v = x2[(size_t)(b_ * 512 + t) * 64 + cth + 16 * k];
                    stg[r_ * 840 + 256 + cth + 16 * k] = f2bf(v * mk);
                }
                // ---- poll-stage h5[t-1]: expect tag t (hybrid L2/IC) ----
                {
                    const u64* src = (const u64*)(h5w + ((t + 1) & 1) * 65536 +
                                                  (size_t)b_ * 512);
                    const u32 exp = (u32)t;
                    u64 v[16];
                    int round = 0;
                    while (true) {
                        if ((round & 7) != 7) {
                            l1_inv();
#pragma unroll
                            for (int k = 0; k < 16; ++k)
                                v[k] = __hip_atomic_load(&src[cth + 16 * k], __ATOMIC_RELAXED, WGSC);
                        } else {
#pragma unroll
                            for (int k = 0; k < 16; ++k)
                                v[k] = __hip_atomic_load(&src[cth + 16 * k], __ATOMIC_RELAXED, AGENT);
                        }
                        bool ok = true;
#pragma unroll
                        for (int k = 0; k < 16; ++k) {
                            u32 lo = (u32)v[k], hi = (u32)(v[k] >> 32);
                            if (((lo >> 16) != exp) | ((hi >> 16) != exp)) ok = false;
                        }
                        if (ok) break;
                        if ((round & 7) == 7) __builtin_amdgcn_s_sleep(1);
                        ++round;
                    }
                    u16* dst = &stg[r_ * 840 + 320];
#pragma unroll
                    for (int k = 0; k < 16; ++k) {
                        u32 lo = (u32)v[k], hi = (u32)(v[k] >> 32);
                        int c = (cth + 16 * k) * 2;
                        *(u32*)&dst[c] = (lo & 0xffffu) | (hi << 16);
                    }
                }
                // ---- WAR guard (pre-barrier, off post-MFMA path): GRU6 must
                //      have finished iter t-1 (h6 tag t-1 in slot t&1) ----
                if (t >= 2 && wv == 0) {
                    const u32 exp6 = (u32)(t - 1);
                    const u32* q = h6w + (t & 1) * 65536 + (size_t)row0 * 512 + (lane & 15) * 32;
                    int round = 0;
                    while (true) {
                        u32 w;
                        if ((round & 7) != 7) {
                            l1_inv();
                            w = __hip_atomic_load(q, __ATOMIC_RELAXED, WGSC);
                        } else {
                            w = __hip_atomic_load(q, __ATOMIC_RELAXED, AGENT);
                        }
                        if (__all((int)((w >> 16) >= exp6))) break;
                        if ((round & 7) == 7) __builtin_amdgcn_s_sleep(1);
                        ++round;
                    }
                }
                __syncthreads();
                // ---- MFMA: x-part K=320 (W5), h-part K=512 (U5) ----
                f32x4 a0 = {biasM, biasM, biasM, biasM};
                f32x4 a1 = {biasS, biasS, biasS, biasS};
                if (wv < 2) {  // z + xh
#pragma unroll
                    for (int kt = 0; kt < 10; ++kt) {
                        bf16x8 a = ldsA(stg, 840, kt * 32, l15, q8);
                        a0 = MFMA(a, Bm[kt], a0);
                        a1 = MFMA(a, Bs[kt], a1);
                    }
#pragma unroll
                    for (int kt = 0; kt < 16; ++kt) {
                        bf16x8 a = ldsA(stg, 840, 320 + kt * 32, l15, q8);
                        a0 = MFMA(a, Bm[10 + kt], a0);
                    }
                } else {       // r + ih
#pragma unroll
                    for (int kt = 0; kt < 10; ++kt) {
                        bf16x8 a = ldsA(stg, 840, kt * 32, l15, q8);
                        a0 = MFMA(a, Bm[kt], a0);
                    }
#pragma unroll
                    for (int kt = 0; kt < 16; ++kt) {
                        bf16x8 a = ldsA(stg, 840, 320 + kt * 32, l15, q8);
                        a0 = MFMA(a, Bm[10 + kt], a0);
                        a1 = MFMA(a, Bs[kt], a1);
                    }
                }
                {
                    int uM = gMain * 2 + ct, uS = (wv < 2 ? 4 + ct : 6 + ct);
#pragma unroll
                    for (int i = 0; i < 4; ++i) {
                        int rr = (lane >> 4) * 4 + i;
                        exch[uM * 272 + rr * 17 + l15] = a0[i];
                        exch[uS * 272 + rr * 17 + l15] = a1[i];
                    }
                }
                __syncthreads();
                // ---- gate math; fp32 regs; tagged u64 agent store ----
                {
                    int base0 = (0 + c2p) * 272 + grow * 17 + ccb;
                    int base1 = (2 + c2p) * 272 + grow * 17 + ccb;
                    int base2 = (4 + c2p) * 272 + grow * 17 + ccb;
                    int base3 = (6 + c2p) * 272 + grow * 17 + ccb;
                    float zv0 = exch[base0], zv1 = exch[base0 + 1];
                    float rv0 = exch[base1], rv1 = exch[base1 + 1];
                    float xh0 = exch[base2], xh1 = exch[base2 + 1];
                    float ih0 = exch[base3], ih1 = exch[base3 + 1];
                    float zg0 = sat01(0.2f * zv0 + 0.5f), zg1 = sat01(0.2f * zv1 + 0.5f);
                    float rt0 = sat01(0.2f * rv0 + 0.5f), rt1 = sat01(0.2f * rv1 + 0.5f);
                    float hh0 = ftanh(xh0 + rt0 * ih0), hh1 = ftanh(xh1 + rt1 * ih1);
                    float h0 = zg0 * hold0 + (1.f - zg0) * hh0;
                    float h1 = zg1 * hold1 + (1.f - zg1) * hh1;
                    hold0 = h0; hold1 = h1;
                    const u32 tg = (u32)(t + 1) << 16;
                    u64 w = ((u64)(tg | (u32)f2bf(h1)) << 32) | (u64)(tg | (u32)f2bf(h0));
                    u64* dst = (u64*)(h5w + (t & 1) * 65536 + (size_t)row0 * 512);
                    __hip_atomic_store(&dst[(grow * 512 + sb + cp * 2) >> 1], w,
                                       __ATOMIC_RELAXED, AGENT);
                }
            }
        } else {
            // ---- poll-stage g5=h5[t-1] (tag t, t<=512) and h6[t-2] (tag t-1) ----
            if (t >= 1) {
                const u64* s2 = (const u64*)(h6w + (t & 1) * 65536 + (size_t)b_ * 512);
                const u32 exp2 = (u32)(t - 1);
                if (t <= 512) {
                    const u64* s1 = (const u64*)(h5w + ((t + 1) & 1) * 65536 + (size_t)b_ * 512);
                    const u32 exp1 = (u32)t;
                    u64 v1[16], v2[16];
                    int round = 0;
                    while (true) {
                        if ((round & 7) != 7) {
                            l1_inv();
#pragma unroll
                            for (int k = 0; k < 16; ++k) {
                                v1[k] = __hip_atomic_load(&s1[cth + 16 * k], __ATOMIC_RELAXED, WGSC);
                                v2[k] = __hip_atomic_load(&s2[cth + 16 * k], __ATOMIC_RELAXED, WGSC);
                            }
                        } else {
#pragma unroll
                            for (int k = 0; k < 16; ++k) {
                                v1[k] = __hip_atomic_load(&s1[cth + 16 * k], __ATOMIC_RELAXED, AGENT);
                                v2[k] = __hip_atomic_load(&s2[cth + 16 * k], __ATOMIC_RELAXED, AGENT);
                            }
                        }
                        bool ok = true;
#pragma unroll
                        for (int k = 0; k < 16; ++k) {
                            u32 lo1 = (u32)v1[k], hi1 = (u32)(v1[k] >> 32);
                            u32 lo2 = (u32)v2[k], hi2 = (u32)(v2[k] >> 32);
                            if (((lo1 >> 16) != exp1) | ((hi1 >> 16) != exp1) |
                                ((lo2 >> 16) != exp2) | ((hi2 >> 16) != exp2)) ok = false;
                        }
                        if (ok) break;
                        if ((round & 7) == 7) __builtin_amdgcn_s_sleep(1);
                        ++round;
                    }
#pragma unroll
                    for (int k = 0; k < 16; ++k) {
                        int c = (cth + 16 * k) * 2;
                        u32 lo = (u32)v1[k], hi = (u32)(v1[k] >> 32);
                        *(u32*)&stg[r_ * 1032 + c] = (lo & 0xffffu) | (hi << 16);
                        lo = (u32)v2[k]; hi = (u32)(v2[k] >> 32);
                        *(u32*)&stg[r_ * 1032 + 512 + c] = (lo & 0xffffu) | (hi << 16);
                    }
                } else {  // t == 513: only h6[511] needed (for dec)
                    u64 v2[16];
                    int round = 0;
                    while (true) {
                        if ((round & 7) != 7) {
                            l1_inv();
#pragma unroll
                            for (int k = 0; k < 16; ++k)
                                v2[k] = __hip_atomic_load(&s2[cth + 16 * k], __ATOMIC_RELAXED, WGSC);
                        } else {
#pragma unroll
                            for (int k = 0; k < 16; ++k)
                                v2[k] = __hip_atomic_load(&s2[cth + 16 * k], __ATOMIC_RELAXED, AGENT);
                        }
                        bool ok = true;
#pragma unroll
                        for (int k = 0; k < 16; ++k) {
                            u32 lo = (u32)v2[k], hi = (u32)(v2[k] >> 32);
                            if (((lo >> 16) != exp2) | ((hi >> 16) != exp2)) ok = false;
                        }
                        if (ok) break;
                        if ((round & 7) == 7) __builtin_amdgcn_s_sleep(1);
                        ++round;
                    }
#pragma unroll
                    for (int k = 0; k < 16; ++k) {
                        int c = (cth + 16 * k) * 2;
                        u32 lo = (u32)v2[k], hi = (u32)(v2[k] >> 32);
                        *(u32*)&stg[r_ * 1032 + 512 + c] = (lo & 0xffffu) | (hi << 16);
                    }
                }
            }
            __syncthreads();
            if (t >= 1 && t <= 512) {
                f32x4 a0 = {biasM, biasM, biasM, biasM};
                f32x4 a1 = {biasS, biasS, biasS, biasS};
                if (wv < 2) {  // z + xh
#pragma unroll
                    for (int kt = 0; kt < 16; ++kt) {
                        bf16x8 a = ldsA(stg, 1032, kt * 32, l15, q8);
                        a0 = MFMA(a, Bm[kt], a0);
                        a1 = MFMA(a, Bs[kt], a1);
                    }
#pragma unroll
                    for (int kt = 0; kt < 16; ++kt) {
                        bf16x8 a = ldsA(stg, 1032, 512 + kt * 32, l15, q8);
                        a0 = MFMA(a, Bm[16 + kt], a0);
                    }
                } else {       // r + ih
#pragma unroll
                    for (int kt = 0; kt < 16; ++kt) {
                        bf16x8 a = ldsA(stg, 1032, kt * 32, l15, q8);
                        a0 = MFMA(a, Bm[kt], a0);
                    }
#pragma unroll
                    for (int kt = 0; kt < 16; ++kt) {
                        bf16x8 a = ldsA(stg, 1032, 512 + kt * 32, l15, q8);
                        a0 = MFMA(a, Bm[16 + kt], a0);
                        a1 = MFMA(a, Bs[kt], a1);
                    }
                }
                {
                    int uM = gMain * 2 + ct, uS = (wv < 2 ? 4 + ct : 6 + ct);
#pragma unroll
                    for (int i = 0; i < 4; ++i) {
                        int rr = (lane >> 4) * 4 + i;
                        exch[uM * 272 + rr * 17 + l15] = a0[i];
                        exch[uS * 272 + rr * 17 + l15] = a1[i];
                    }
                }
                __syncthreads();
                {
                    int base0 = (0 + c2p) * 272 + grow * 17 + ccb;
                    int base1 = (2 + c2p) * 272 + grow * 17 + ccb;
                    int base2 = (4 + c2p) * 272 + grow * 17 + ccb;
                    int base3 = (6 + c2p) * 272 + grow * 17 + ccb;
                    float zv0 = exch[base0], zv1 = exch[base0 + 1];
                    float rv0 = exch[base1], rv1 = exch[base1 + 1];
                    float xh0 = exch[base2], xh1 = exch[base2 + 1];
                    float ih0 = exch[base3], ih1 = exch[base3 + 1];
                    float zg0 = sat01(0.2f * zv0 + 0.5f), zg1 = sat01(0.2f * zv1 + 0.5f);
                    float rt0 = sat01(0.2f * rv0 + 0.5f), rt1 = sat01(0.2f * rv1 + 0.5f);
                    float hh0 = ftanh(xh0 + rt0 * ih0), hh1 = ftanh(xh1 + rt1 * ih1);
                    float h0 = zg0 * hold0 + (1.f - zg0) * hh0;
                    float h1 = zg1 * hold1 + (1.f - zg1) * hh1;
                    hold0 = h0; hold1 = h1;
                    const u32 tg = (u32)t << 16;   // h6[t-1] stamped (t-1)+1 = t
                    u64 w = ((u64)(tg | (u32)f2bf(h1)) << 32) | (u64)(tg | (u32)f2bf(h0));
                    u64* dst = (u64*)(h6w + ((t + 1) & 1) * 65536 + (size_t)row0 * 512);
                    __hip_atomic_store(&dst[(grow * 512 + sb + cp * 2) >> 1], w,
                                       __ATOMIC_RELAXED, AGENT);
                }
            }
            // dec[t-2] from LDS-staged h6[t-2]
            if (t >= 2 && wv == 0) {
                const u16* hrow = &stg[slice * 1032 + 512 + lane * 8];
                bf16x8 hv = *(const bf16x8*)hrow;
                float s = 0.f;
#pragma unroll
                for (int j = 0; j < 8; ++j) s += bf2f((u16)hv[j]) * wdv[j];
#pragma unroll
                for (int off = 32; off >= 1; off >>= 1) s += __shfl_down(s, off);
                if (lane == 0) {
                    int bb = row0 + slice, tt = t - 2;
                    out[bb * 512 + tt] = ftanh(s + bdv) * dmsk[bb * 512 + tt];
                }
            }
            __syncthreads();   // protect stg reuse across iterations
        }
    }
}

extern "C" void kernel_launch(void* const* d_in, const int* in_sizes, int n_in,
                              void* d_out, int out_size, void* d_ws, size_t ws_size,
                              hipStream_t stream) {
    const float* zin = (const float*)d_in[0];
    const float* x2  = (const float*)d_in[1];
    const float* msk = (const float*)d_in[2];
    const float* dmk = (const float*)d_in[3];
    const float* W5  = (const float*)d_in[4];
    const float* U5  = (const float*)d_in[5];
    const float* bi5 = (const float*)d_in[6];
    const float* br5 = (const float*)d_in[7];
    const float* W6  = (const float*)d_in[8];
    const float* U6  = (const float*)d_in[9];
    const float* bi6 = (const float*)d_in[10];
    const float* br6 = (const float*)d_in[11];
    const float* Wd  = (const float*)d_in[12];
    const float* bd  = (const float*)d_in[13];
    float* out = (float*)d_out;

    // ws (u32 units): h5w [2][128][512] | h6w [2][128][512]
    u32* h5w = (u32*)d_ws;                 // 512 KB
    u32* h6w = h5w + 131072;               // 512 KB

    zero_ws_kernel<<<dim3(1024), dim3(256), 0, stream>>>((u32*)d_ws);

    gru_fused<<<dim3(256), dim3(256), 0, stream>>>(
        zin, x2, msk, dmk, W5, U5, bi5, br5, W6, U6, bi6, br6,
        Wd, bd, out, h5w, h6w);
}

// Round 3
// 2037.844 us; speedup vs baseline: 1.2842x; 1.2842x over previous
//
#include <hip/hip_runtime.h>
#include <hip/hip_bf16.h>

typedef unsigned short u16;
typedef unsigned int u32;
typedef unsigned long long u64;
typedef __attribute__((ext_vector_type(8))) short bf16x8;   // 8 bf16 (4 VGPRs)
typedef __attribute__((ext_vector_type(4))) float f32x4;

#define MFMA(a,b,c) __builtin_amdgcn_mfma_f32_16x16x32_bf16((a),(b),(c),0,0,0)
#define AGENT __HIP_MEMORY_SCOPE_AGENT
#define WGSC  __HIP_MEMORY_SCOPE_WORKGROUP

// v4: guaranteed-XCD-local exchange via HW_REG_XCC_ID role claiming.
// Model established by v1/v2/v3 measurements:
//   - agent atomic store: write-through to IC, does NOT update local L2
//   - agent atomic load: bypasses L1+L2, served by IC (~900cy)
//   - plain store: write-through L1 -> lands in local XCD L2 (fresh there)
//   - plain load: L1/L2 cached; sc0/buffer_inv semantics unreliable
// => same-XCD plain/plain is the only fast path; it needs GUARANTEED
// co-location and an unconditional agent fallback.
// Claiming: wg reads its physical XCD (s_getreg HW_REG_XCC_ID), tickets
// claim[xcd] (agent RMW). 40KB LDS pad forces 1 wg/CU, so 256 wgs <-> 256
// CUs bijection => exactly 32 wgs per XCD. Consensus: spin until
// sum(claim)==256 (bounded: claiming precedes all inter-wg deps), then
// good <=> all claim[g]==32; identical verdict everywhere; bad => v1
// mapping + pure-agent protocol.
// Local protocol: producers double-store each tagged word (plain -> local
// L2, then agent -> IC); consumers alternate plain rounds (L2, fast+fresh)
// and agent rounds (IC, unconditionally correct). No hang mode exists.
// Buffers 4-deep (slot = tag&3); GRU5 WAR guard relaxed to h6 tag >= t-3
// (slack 3, off critical path; also kills all slot-clobber races under
// the larger skew the fast path allows).
//
// B=128, T=512, LAT=256, F2=64, H=512, DIN=320, 3H=1536
// roles: rgp 0..7 (16 rows), rid 0..31: rid<16 GRU5 slice, else GRU6 slice.
// iter t (514): GRU5 -> h5[t] (t<512, tag t+1, slot (t+1)&3);
//   GRU6 -> h6[t-1] (1<=t<=512, tag t, slot t&3); dec[t-2] (t>=2).
// Tags: every h word u32 = (step_tag<<16)|bf16, self-validating per word.

__device__ __forceinline__ u16 f2bf(float f) {
    u32 u = __float_as_uint(f);
    u32 r = (u + 0x7fffu + ((u >> 16) & 1u)) >> 16;
    return (u16)r;
}
__device__ __forceinline__ float bf2f(u16 v) { return __uint_as_float(((u32)v) << 16); }
__device__ __forceinline__ float sat01(float x) { return fminf(1.f, fmaxf(0.f, x)); }
__device__ __forceinline__ float ftanh(float x) {
    x = fminf(10.f, fmaxf(-10.f, x));
    float e = __expf(2.f * x);
    return (e - 1.f) / (e + 1.f);
}

__device__ __forceinline__ bf16x8 loadB(const float* __restrict__ M, int k0, int colbase,
                                        int l15, int q8) {
    const float* p = M + (size_t)(k0 + q8) * 1536 + colbase + l15;
    bf16x8 r;
#pragma unroll
    for (int j = 0; j < 8; ++j) r[j] = (short)f2bf(p[(size_t)j * 1536]);
    return r;
}

__device__ __forceinline__ bf16x8 ldsA(const u16* s, int stride, int colbase, int l15, int q8) {
    return *(const bf16x8*)(s + l15 * stride + colbase + q8);
}

__global__ void zero_ws_kernel(u32* ws) {
    int i = blockIdx.x * 256 + threadIdx.x;
    if (i < 524296) ws[i] = 0u;  // h5w[4][128][512] + h6w[4][128][512] + claim[8]
}

__global__ void __launch_bounds__(256, 1)
gru_fused(const float* __restrict__ zin, const float* __restrict__ x2,
          const float* __restrict__ msk, const float* __restrict__ dmsk,
          const float* __restrict__ W5, const float* __restrict__ U5,
          const float* __restrict__ bi5, const float* __restrict__ br5,
          const float* __restrict__ W6, const float* __restrict__ U6,
          const float* __restrict__ bi6, const float* __restrict__ br6,
          const float* __restrict__ Wd, const float* __restrict__ bdp,
          float* __restrict__ out, u32* __restrict__ h5w,
          u32* __restrict__ h6w, u32* __restrict__ claim)
{
    const int wg = blockIdx.x;
    const int tid = threadIdx.x;
    const int wv = tid >> 6, lane = tid & 63;
    const int l15 = lane & 15, q8 = (lane >> 4) << 3;

    __shared__ u16 stg[16 * 1032];
    __shared__ float exch[8 * 16 * 17];
    __shared__ u32 lds_pad[10240];   // 40KB: total LDS > 80KB -> 1 wg/CU forced
    __shared__ u32 s_tk, s_good;

    ((volatile u32*)lds_pad)[tid] = 0u;   // keep pad alive

    // ---- XCD role claiming + deterministic consensus ----
    const int xcd = (int)(__builtin_amdgcn_s_getreg((31u << 11) | 20u) & 7u); // HW_REG_XCC_ID
    if (tid == 0) {
        u32 tk = __hip_atomic_fetch_add(&claim[xcd], 1u, __ATOMIC_RELAXED, AGENT);
        s_tk = tk;
        u32 c[8]; u32 tot;
        do {
            tot = 0;
#pragma unroll
            for (int g = 0; g < 8; ++g) {
                c[g] = __hip_atomic_load(&claim[g], __ATOMIC_RELAXED, AGENT);
                tot += c[g];
            }
            if (tot < 256u) __builtin_amdgcn_s_sleep(8);
        } while (tot < 256u);
        u32 good = 1u;
#pragma unroll
        for (int g = 0; g < 8; ++g) if (c[g] != 32u) good = 0u;
        s_good = good;
    }
    __syncthreads();
    const bool lcl = (s_good != 0u);
    const int rgp = lcl ? xcd : (wg & 7);
    const int rid = lcl ? (int)s_tk : (wg >> 3);
    const bool is6 = rid >= 16;
    const int slice = is6 ? (rid - 16) : rid;
    const int row0 = rgp << 4;
    const int sb = slice << 5;

    const int ct = wv & 1;
    const int gMain = (wv < 2) ? 0 : 1;
    const int colMain = gMain * 512 + sb + ct * 16;
    const int colH = 1024 + sb + ct * 16;

    const float* bi = is6 ? bi6 : bi5;
    const float* br = is6 ? br6 : br5;
    const float biasM = bi[colMain + l15] + br[colMain + l15];
    const float biasS = (wv < 2) ? bi[colH + l15] : br[colH + l15];

    bf16x8 Bm[32], Bs[16];
    if (!is6) {
#pragma unroll
        for (int kt = 0; kt < 10; ++kt) Bm[kt] = loadB(W5, kt * 32, colMain, l15, q8);
#pragma unroll
        for (int kt = 0; kt < 16; ++kt) Bm[10 + kt] = loadB(U5, kt * 32, colMain, l15, q8);
        if (wv < 2) {
#pragma unroll
            for (int kt = 0; kt < 10; ++kt) Bs[kt] = loadB(W5, kt * 32, colH, l15, q8);
        } else {
#pragma unroll
            for (int kt = 0; kt < 16; ++kt) Bs[kt] = loadB(U5, kt * 32, colH, l15, q8);
        }
    } else {
#pragma unroll
        for (int kt = 0; kt < 16; ++kt) Bm[kt] = loadB(W6, kt * 32, colMain, l15, q8);
#pragma unroll
        for (int kt = 0; kt < 16; ++kt) Bm[16 + kt] = loadB(U6, kt * 32, colMain, l15, q8);
        if (wv < 2) {
#pragma unroll
            for (int kt = 0; kt < 16; ++kt) Bs[kt] = loadB(W6, kt * 32, colH, l15, q8);
        } else {
#pragma unroll
            for (int kt = 0; kt < 16; ++kt) Bs[kt] = loadB(U6, kt * 32, colH, l15, q8);
        }
    }

    float wdv[8]; float bdv = 0.f;
    if (is6 && wv == 0) {
#pragma unroll
        for (int j = 0; j < 8; ++j) wdv[j] = Wd[lane * 8 + j];
        bdv = bdp[0];
    }

    const int grow = tid >> 4, cp = tid & 15;
    const int c2p = cp >> 3, ccb = (cp & 7) * 2;
    const int r_ = tid >> 4, cth = tid & 15;
    const int b_ = row0 + r_;

    // zin row is t-invariant: stage once to registers (16 f32/thread)
    float zreg[16];
#pragma unroll
    for (int k = 0; k < 16; ++k) zreg[k] = zin[(size_t)b_ * 256 + cth + 16 * k];

    float hold0 = 0.f, hold1 = 0.f;

    for (int t = 0; t < 514; ++t) {
        if (!is6) {
            if (t < 512) {
                // ---- stage masked x (independent of h; issued first) ----
                float mk = msk[b_ * 512 + t];
#pragma unroll
                for (int k = 0; k < 16; ++k)
                    stg[r_ * 840 + cth + 16 * k] = f2bf(zreg[k] * mk);
#pragma unroll
                for (int k = 0; k < 4; ++k) {
                    float v = x2[(size_t)(b_ * 512 + t) * 64 + cth + 16 * k];
                    stg[r_ * 840 + 256 + cth + 16 * k] = f2bf(v * mk);
                }
                // ---- poll-stage h5[t-1]: tag t, slot t&3 (dual-cadence) ----
                {
                    const u64* src = (const u64*)(h5w + (size_t)(t & 3) * 65536 +
                                                  (size_t)b_ * 512);
                    const u32 exp = (u32)t;
                    u64 v[16];
                    int round = 0;
                    while (true) {
                        const bool ag = (!lcl) || ((round & 1) == 1);
                        if (ag) {
#pragma unroll
                            for (int k = 0; k < 16; ++k)
                                v[k] = __hip_atomic_load(&src[cth + 16 * k], __ATOMIC_RELAXED, AGENT);
                        } else {
#pragma unroll
                            for (int k = 0; k < 16; ++k)
                                v[k] = __hip_atomic_load(&src[cth + 16 * k], __ATOMIC_RELAXED, WGSC);
                        }
                        bool ok = true;
#pragma unroll
                        for (int k = 0; k < 16; ++k) {
                            u32 lo = (u32)v[k], hi = (u32)(v[k] >> 32);
                            if (((lo >> 16) != exp) | ((hi >> 16) != exp)) ok = false;
                        }
                        if (ok) break;
                        if (ag) __builtin_amdgcn_s_sleep(1);
                        ++round;
                    }
                    u16* dst = &stg[r_ * 840 + 320];
#pragma unroll
                    for (int k = 0; k < 16; ++k) {
                        u32 lo = (u32)v[k], hi = (u32)(v[k] >> 32);
                        int c = (cth + 16 * k) * 2;
                        *(u32*)&dst[c] = (lo & 0xffffu) | (hi << 16);
                    }
                }
                // ---- WAR guard, slack 3 (rarely binds): GRU6 must have
                //      finished iter t-3 (h6 tag >= t-3 in slot (t-3)&3) ----
                if (t >= 4 && wv == 0) {
                    const u32 exp6 = (u32)(t - 3);
                    const u32* q = h6w + (size_t)((t - 3) & 3) * 65536 +
                                   (size_t)row0 * 512 + (lane & 15) * 32;
                    int round = 0;
                    while (true) {
                        const bool ag = (!lcl) || ((round & 1) == 1);
                        u32 w = ag ? __hip_atomic_load(q, __ATOMIC_RELAXED, AGENT)
                                   : __hip_atomic_load(q, __ATOMIC_RELAXED, WGSC);
                        if (__all((int)((w >> 16) >= exp6))) break;
                        if (ag) __builtin_amdgcn_s_sleep(1);
                        ++round;
                    }
                }
                __syncthreads();
                // ---- MFMA: x-part K=320 (W5), h-part K=512 (U5) ----
                f32x4 a0 = {biasM, biasM, biasM, biasM};
                f32x4 a1 = {biasS, biasS, biasS, biasS};
                if (wv < 2) {  // z + xh
#pragma unroll
                    for (int kt = 0; kt < 10; ++kt) {
                        bf16x8 a = ldsA(stg, 840, kt * 32, l15, q8);
                        a0 = MFMA(a, Bm[kt], a0);
                        a1 = MFMA(a, Bs[kt], a1);
                    }
#pragma unroll
                    for (int kt = 0; kt < 16; ++kt) {
                        bf16x8 a = ldsA(stg, 840, 320 + kt * 32, l15, q8);
                        a0 = MFMA(a, Bm[10 + kt], a0);
                    }
                } else {       // r + ih
#pragma unroll
                    for (int kt = 0; kt < 10; ++kt) {
                        bf16x8 a = ldsA(stg, 840, kt * 32, l15, q8);
                        a0 = MFMA(a, Bm[kt], a0);
                    }
#pragma unroll
                    for (int kt = 0; kt < 16; ++kt) {
                        bf16x8 a = ldsA(stg, 840, 320 + kt * 32, l15, q8);
                        a0 = MFMA(a, Bm[10 + kt], a0);
                        a1 = MFMA(a, Bs[kt], a1);
                    }
                }
                {
                    int uM = gMain * 2 + ct, uS = (wv < 2 ? 4 + ct : 6 + ct);
#pragma unroll
                    for (int i = 0; i < 4; ++i) {
                        int rr = (lane >> 4) * 4 + i;
                        exch[uM * 272 + rr * 17 + l15] = a0[i];
                        exch[uS * 272 + rr * 17 + l15] = a1[i];
                    }
                }
                __syncthreads();
                // ---- gate math; tagged u64 dual store ----
                {
                    int base0 = (0 + c2p) * 272 + grow * 17 + ccb;
                    int base1 = (2 + c2p) * 272 + grow * 17 + ccb;
                    int base2 = (4 + c2p) * 272 + grow * 17 + ccb;
                    int base3 = (6 + c2p) * 272 + grow * 17 + ccb;
                    float zv0 = exch[base0], zv1 = exch[base0 + 1];
                    float rv0 = exch[base1], rv1 = exch[base1 + 1];
                    float xh0 = exch[base2], xh1 = exch[base2 + 1];
                    float ih0 = exch[base3], ih1 = exch[base3 + 1];
                    float zg0 = sat01(0.2f * zv0 + 0.5f), zg1 = sat01(0.2f * zv1 + 0.5f);
                    float rt0 = sat01(0.2f * rv0 + 0.5f), rt1 = sat01(0.2f * rv1 + 0.5f);
                    float hh0 = ftanh(xh0 + rt0 * ih0), hh1 = ftanh(xh1 + rt1 * ih1);
                    float h0 = zg0 * hold0 + (1.f - zg0) * hh0;
                    float h1 = zg1 * hold1 + (1.f - zg1) * hh1;
                    hold0 = h0; hold1 = h1;
                    const u32 tg = (u32)(t + 1) << 16;
                    u64 w = ((u64)(tg | (u32)f2bf(h1)) << 32) | (u64)(tg | (u32)f2bf(h0));
                    u64* dst = (u64*)(h5w + (size_t)((t + 1) & 3) * 65536 +
                                      (size_t)row0 * 512);
                    u64* p = &dst[(grow * 512 + sb + cp * 2) >> 1];
                    if (lcl) __hip_atomic_store(p, w, __ATOMIC_RELAXED, WGSC);  // local L2
                    __hip_atomic_store(p, w, __ATOMIC_RELAXED, AGENT);          // IC copy
                }
            }
        } else {
            // ---- poll-stage g5=h5[t-1] (tag t, slot t&3, t<=512) and
            //      h6[t-2] (tag t-1, slot (t-1)&3, t>=1) ----
            if (t >= 1) {
                const u64* s2 = (const u64*)(h6w + (size_t)((t - 1) & 3) * 65536 +
                                             (size_t)b_ * 512);
                const u32 exp2 = (u32)(t - 1);
                if (t <= 512) {
                    const u64* s1 = (const u64*)(h5w + (size_t)(t & 3) * 65536 +
                                                 (size_t)b_ * 512);
                    const u32 exp1 = (u32)t;
                    u64 v1[16], v2[16];
                    int round = 0;
                    while (true) {
                        const bool ag = (!lcl) || ((round & 1) == 1);
                        if (ag) {
#pragma unroll
                            for (int k = 0; k < 16; ++k) {
                                v1[k] = __hip_atomic_load(&s1[cth + 16 * k], __ATOMIC_RELAXED, AGENT);
                                v2[k] = __hip_atomic_load(&s2[cth + 16 * k], __ATOMIC_RELAXED, AGENT);
                            }
                        } else {
#pragma unroll
                            for (int k = 0; k < 16; ++k) {
                                v1[k] = __hip_atomic_load(&s1[cth + 16 * k], __ATOMIC_RELAXED, WGSC);
                                v2[k] = __hip_atomic_load(&s2[cth + 16 * k], __ATOMIC_RELAXED, WGSC);
                            }
                        }
                        bool ok = true;
#pragma unroll
                        for (int k = 0; k < 16; ++k) {
                            u32 lo1 = (u32)v1[k], hi1 = (u32)(v1[k] >> 32);
                            u32 lo2 = (u32)v2[k], hi2 = (u32)(v2[k] >> 32);
                            if (((lo1 >> 16) != exp1) | ((hi1 >> 16) != exp1) |
                                ((lo2 >> 16) != exp2) | ((hi2 >> 16) != exp2)) ok = false;
                        }
                        if (ok) break;
                        if (ag) __builtin_amdgcn_s_sleep(1);
                        ++round;
                    }
#pragma unroll
                    for (int k = 0; k < 16; ++k) {
                        int c = (cth + 16 * k) * 2;
                        u32 lo = (u32)v1[k], hi = (u32)(v1[k] >> 32);
                        *(u32*)&stg[r_ * 1032 + c] = (lo & 0xffffu) | (hi << 16);
                        lo = (u32)v2[k]; hi = (u32)(v2[k] >> 32);
                        *(u32*)&stg[r_ * 1032 + 512 + c] = (lo & 0xffffu) | (hi << 16);
                    }
                } else {  // t == 513: only h6[511] needed (for dec)
                    u64 v2[16];
                    int round = 0;
                    while (true) {
                        const bool ag = (!lcl) || ((round & 1) == 1);
                        if (ag) {
#pragma unroll
                            for (int k = 0; k < 16; ++k)
                                v2[k] = __hip_atomic_load(&s2[cth + 16 * k], __ATOMIC_RELAXED, AGENT);
                        } else {
#pragma unroll
                            for (int k = 0; k < 16; ++k)
                                v2[k] = __hip_atomic_load(&s2[cth + 16 * k], __ATOMIC_RELAXED, WGSC);
                        }
                        bool ok = true;
#pragma unroll
                        for (int k = 0; k < 16; ++k) {
                            u32 lo = (u32)v2[k], hi = (u32)(v2[k] >> 32);
                            if (((lo >> 16) != exp2) | ((hi >> 16) != exp2)) ok = false;
                        }
                        if (ok) break;
                        if (ag) __builtin_amdgcn_s_sleep(1);
                        ++round;
                    }
#pragma unroll
                    for (int k = 0; k < 16; ++k) {
                        int c = (cth + 16 * k) * 2;
                        u32 lo = (u32)v2[k], hi = (u32)(v2[k] >> 32);
                        *(u32*)&stg[r_ * 1032 + 512 + c] = (lo & 0xffffu) | (hi << 16);
                    }
                }
            }
            __syncthreads();
            if (t >= 1 && t <= 512) {
                f32x4 a0 = {biasM, biasM, biasM, biasM};
                f32x4 a1 = {biasS, biasS, biasS, biasS};
                if (wv < 2) {  // z + xh
#pragma unroll
                    for (int kt = 0; kt < 16; ++kt) {
                        bf16x8 a = ldsA(stg, 1032, kt * 32, l15, q8);
                        a0 = MFMA(a, Bm[kt], a0);
                        a1 = MFMA(a, Bs[kt], a1);
                    }
#pragma unroll
                    for (int kt = 0; kt < 16; ++kt) {
                        bf16x8 a = ldsA(stg, 1032, 512 + kt * 32, l15, q8);
                        a0 = MFMA(a, Bm[16 + kt], a0);
                    }
                } else {       // r + ih
#pragma unroll
                    for (int kt = 0; kt < 16; ++kt) {
                        bf16x8 a = ldsA(stg, 1032, kt * 32, l15, q8);
                        a0 = MFMA(a, Bm[kt], a0);
                    }
#pragma unroll
                    for (int kt = 0; kt < 16; ++kt) {
                        bf16x8 a = ldsA(stg, 1032, 512 + kt * 32, l15, q8);
                        a0 = MFMA(a, Bm[16 + kt], a0);
                        a1 = MFMA(a, Bs[kt], a1);
                    }
                }
                {
                    int uM = gMain * 2 + ct, uS = (wv < 2 ? 4 + ct : 6 + ct);
#pragma unroll
                    for (int i = 0; i < 4; ++i) {
                        int rr = (lane >> 4) * 4 + i;
                        exch[uM * 272 + rr * 17 + l15] = a0[i];
                        exch[uS * 272 + rr * 17 + l15] = a1[i];
                    }
                }
                __syncthreads();
                {
                    int base0 = (0 + c2p) * 272 + grow * 17 + ccb;
                    int base1 = (2 + c2p) * 272 + grow * 17 + ccb;
                    int base2 = (4 + c2p) * 272 + grow * 17 + ccb;
                    int base3 = (6 + c2p) * 272 + grow * 17 + ccb;
                    float zv0 = exch[base0], zv1 = exch[base0 + 1];
                    float rv0 = exch[base1], rv1 = exch[base1 + 1];
                    float xh0 = exch[base2], xh1 = exch[base2 + 1];
                    float ih0 = exch[base3], ih1 = exch[base3 + 1];
                    float zg0 = sat01(0.2f * zv0 + 0.5f), zg1 = sat01(0.2f * zv1 + 0.5f);
                    float rt0 = sat01(0.2f * rv0 + 0.5f), rt1 = sat01(0.2f * rv1 + 0.5f);
                    float hh0 = ftanh(xh0 + rt0 * ih0), hh1 = ftanh(xh1 + rt1 * ih1);
                    float h0 = zg0 * hold0 + (1.f - zg0) * hh0;
                    float h1 = zg1 * hold1 + (1.f - zg1) * hh1;
                    hold0 = h0; hold1 = h1;
                    const u32 tg = (u32)t << 16;   // h6[t-1] stamped (t-1)+1 = t
                    u64 w = ((u64)(tg | (u32)f2bf(h1)) << 32) | (u64)(tg | (u32)f2bf(h0));
                    u64* dst = (u64*)(h6w + (size_t)(t & 3) * 65536 +
                                      (size_t)row0 * 512);
                    u64* p = &dst[(grow * 512 + sb + cp * 2) >> 1];
                    if (lcl) __hip_atomic_store(p, w, __ATOMIC_RELAXED, WGSC);  // local L2
                    __hip_atomic_store(p, w, __ATOMIC_RELAXED, AGENT);          // IC copy
                }
            }
            // dec[t-2] from LDS-staged h6[t-2]
            if (t >= 2 && wv == 0) {
                const u16* hrow = &stg[slice * 1032 + 512 + lane * 8];
                bf16x8 hv = *(const bf16x8*)hrow;
                float s = 0.f;
#pragma unroll
                for (int j = 0; j < 8; ++j) s += bf2f((u16)hv[j]) * wdv[j];
#pragma unroll
                for (int off = 32; off >= 1; off >>= 1) s += __shfl_down(s, off);
                if (lane == 0) {
                    int bb = row0 + slice, tt = t - 2;
                    out[bb * 512 + tt] = ftanh(s + bdv) * dmsk[bb * 512 + tt];
                }
            }
            __syncthreads();   // protect stg reuse across iterations
        }
    }
}

extern "C" void kernel_launch(void* const* d_in, const int* in_sizes, int n_in,
                              void* d_out, int out_size, void* d_ws, size_t ws_size,
                              hipStream_t stream) {
    const float* zin = (const float*)d_in[0];
    const float* x2  = (const float*)d_in[1];
    const float* msk = (const float*)d_in[2];
    const float* dmk = (const float*)d_in[3];
    const float* W5  = (const float*)d_in[4];
    const float* U5  = (const float*)d_in[5];
    const float* bi5 = (const float*)d_in[6];
    const float* br5 = (const float*)d_in[7];
    const float* W6  = (const float*)d_in[8];
    const float* U6  = (const float*)d_in[9];
    const float* bi6 = (const float*)d_in[10];
    const float* br6 = (const float*)d_in[11];
    const float* Wd  = (const float*)d_in[12];
    const float* bd  = (const float*)d_in[13];
    float* out = (float*)d_out;

    // ws (u32 units): h5w [4][128][512] | h6w [4][128][512] | claim[8]
    u32* h5w = (u32*)d_ws;                 // 1 MB
    u32* h6w = h5w + 262144;               // 1 MB
    u32* claim = h6w + 262144;             // 32 B

    zero_ws_kernel<<<dim3(2049), dim3(256), 0, stream>>>((u32*)d_ws);

    gru_fused<<<dim3(256), dim3(256), 0, stream>>>(
        zin, x2, msk, dmk, W5, U5, bi5, br5, W6, U6, bi6, br6,
        Wd, bd, out, h5w, h6w, claim);
}